// Round 11
// baseline (2249.813 us; speedup 1.0000x reference)
//
#include <hip/hip_runtime.h>
#include <hip/hip_fp16.h>

typedef _Float16 f16;
typedef _Float16 f16x8_t __attribute__((ext_vector_type(8)));
typedef float    f32x4_t __attribute__((ext_vector_type(4)));

#define NB  4
#define NC  256
#define NH  256
#define NW  256

// ---------------- kernel 1: convert weights (f,g,h) to f16, row-major [cout][ch] ----
__global__ __launch_bounds__(256) void k_convert_w(
    const float* __restrict__ f_w, const float* __restrict__ g_w,
    const float* __restrict__ h_w, f16* __restrict__ wf)
{
    int id = blockIdx.x * 256 + threadIdx.x;   // 0 .. 131071  (512*256)
    int cout = id >> 8;
    float v;
    if (cout < 128)       v = f_w[id];
    else if (cout < 256)  v = g_w[id - 128*256];
    else                  v = h_w[id - 256*256];
    wf[id] = (f16)v;
}

__device__ __forceinline__ void bar_lds() {
    asm volatile("s_waitcnt lgkmcnt(0)" ::: "memory");
    __builtin_amdgcn_s_barrier();
}

// ---------------- kernel 2: fused conv1x1 (512 couts) + 16x16 maxpool ----------------
// PATTERN-FIX build: 256 blocks x 1024 thr (16 waves); block = 4 adjacent windows
// (64 px wide x 16 rows). Global loads are float4 with 16 lanes per channel-row ->
// 256B contiguous chunks (4x the old 64B; old scattered pattern capped HBM at
// ~1.8 TB/s across R2-R10 regardless of schedule). Loads land px-major in an LDS
// scratch [128ch][64px] fp32 (lane-linear writes); threads then read their 8-ch
// column (2-way bank = free), cvt f16 hi/lo, write the identity-layout MFMA tile.
// Every wave uniform: n=1 fg couts (w*16, hi/lo 2-pass) + n=1 h couts (256+w*16).
// Stage = 1 row x 64 px x 128 ch; 32 stages (16 rows x kc2). 2 barriers/stage.
// LDS: identity dbuf 2x(16KB hi+16KB lo) + scratch 32KB = 96KB -> 1 block/CU.
// Identity layout: (pos,ch) byte = (m*4+ks)<<10 + ((pos&15)|(((ch>>3)&3)<<4))*16
//   + (ch&7)*2, m=pos>>4, ks=ch>>5, XOR ((m&3)<<4) -> A-read lane-linear, 0-conflict.
__global__ __launch_bounds__(1024, 4) void k_pooled_conv(
    const float* __restrict__ x, const f16* __restrict__ wf,
    const float* __restrict__ f_b, const float* __restrict__ g_b,
    const float* __restrict__ h_b,
    float* __restrict__ pooled_fg,   // [B][256][256]
    float* __restrict__ pooledT_h)   // [B][256][256]
{
    __shared__ __align__(16) char smem[98304];  // buf0 32KB | buf1 32KB | scratch 32KB

    const int t    = threadIdx.x;
    const int wave = t >> 6;
    const int lane = t & 63;
    const int l15  = lane & 15;
    const int lg   = lane >> 4;

    const int bid = blockIdx.x;          // 0..255
    const int b   = bid >> 6;
    const int g   = bid & 63;
    const int wi  = g >> 2;              // window row 0..15
    const int wjg = g & 3;               // 4-window column group

    // ---- persistent weight fragments: fg (w*16) + h (256+w*16), 8 k-steps each ----
    f16x8_t fgb[8], hb[8];
    {
        const f16* wrF = wf + (wave*16 + l15) * 256 + lg*8;
        const f16* wrH = wrF + 256*256;
        #pragma unroll
        for (int k = 0; k < 8; k++) {
            fgb[k] = *(const f16x8_t*)(wrF + k*32);
            hb[k]  = *(const f16x8_t*)(wrH + k*32);
        }
    }
    const int cF = wave*16 + l15;
    const float biasF = (cF < 128) ? f_b[cF] : g_b[cF - 128];
    const float biasH = h_b[cF];

    // ---- staging coords ----
    // load: thread covers (c = kc*128 + (t>>4) + k*64, px quad = (t&15)*4), k=0,1
    const int cq   = t >> 4;             // 0..63
    const int quad = t & 15;
    // scratch [c_local 128][px 64] fp32: lane-linear writes
    const unsigned sw0 = (unsigned)(cq * 256 + quad * 16);
    const unsigned sw1 = sw0 + 64u * 256u;
    // scratch-read / identity-write: thread = (pos = t&63, chg = t>>6)
    const int pos = t & 63;
    const int chg = t >> 6;              // 0..15 (8 ch each)
    const unsigned sroff = (unsigned)(chg * 8 * 256 + pos * 4);
    const unsigned idoff = ((unsigned)((pos >> 4)*4 + (chg >> 2)) << 10)
                         + ((unsigned)((pos & 15) | ((chg & 3) << 4)) << 4)
                         ^ ((unsigned)((pos >> 4) & 3) << 4);

    const float* xb = x + (size_t)b * (256u * 65536u);
    const unsigned colbase = (unsigned)(wjg * 64 + quad * 4);

    float r[8];
    auto loadst = [&](int s) {   // stage s: y = s>>1, kc = s&1
        const unsigned rowoff = (unsigned)((wi*16 + (s >> 1)) * 256) + colbase;
        const int kc = s & 1;
        const float* p0 = xb + (size_t)(kc*128 + cq)      * 65536u + rowoff;
        const float* p1 = xb + (size_t)(kc*128 + cq + 64) * 65536u + rowoff;
        float4 a = *(const float4*)p0;
        float4 c = *(const float4*)p1;
        r[0]=a.x; r[1]=a.y; r[2]=a.z; r[3]=a.w;
        r[4]=c.x; r[5]=c.y; r[6]=c.z; r[7]=c.w;
    };
    auto scratch_write = [&]() {
        char* sc = smem + 65536;
        *(float4*)(sc + sw0) = make_float4(r[0], r[1], r[2], r[3]);
        *(float4*)(sc + sw1) = make_float4(r[4], r[5], r[6], r[7]);
    };
    auto xpose = [&](int buf) {  // scratch -> identity tile (hi + lo)
        const char* sc = smem + 65536;
        char* base = smem + buf * 32768;
        f16x8_t hv, lv;
        #pragma unroll
        for (int j = 0; j < 8; j++) {
            float v = *(const float*)(sc + sroff + (unsigned)j * 256u);
            f16 h = (f16)v;
            hv[j] = h;
            lv[j] = (f16)(v - (float)h);
        }
        *(f16x8_t*)(base + idoff)         = hv;
        *(f16x8_t*)(base + 16384 + idoff) = lv;
    };

    f32x4_t accF[4] = {{0,0,0,0},{0,0,0,0},{0,0,0,0},{0,0,0,0}};
    f32x4_t accH[4] = {{0,0,0,0},{0,0,0,0},{0,0,0,0},{0,0,0,0}};
    float vmaxF[4] = {-3.0e38f,-3.0e38f,-3.0e38f,-3.0e38f};
    float vmaxH[4] = {-3.0e38f,-3.0e38f,-3.0e38f,-3.0e38f};

    auto mfmast = [&](int s) {
        const char* base = smem + (s & 1) * 32768;
        const int kb = (s & 1) * 4;      // k-step base for this kc
        #pragma unroll
        for (int m = 0; m < 4; m++) {
            const unsigned sw = ((unsigned)(m & 3)) << 4;
            #pragma unroll
            for (int ks = 0; ks < 4; ks++) {
                const char* p = base + (((unsigned)(m*4 + ks)) << 10)
                              + (((unsigned)lane * 16u) ^ sw);
                f16x8_t ah = *(const f16x8_t*)p;
                f16x8_t al = *(const f16x8_t*)(p + 16384);
                accF[m] = __builtin_amdgcn_mfma_f32_16x16x32_f16(ah, fgb[kb+ks], accF[m], 0,0,0);
                accH[m] = __builtin_amdgcn_mfma_f32_16x16x32_f16(ah, hb[kb+ks],  accH[m], 0,0,0);
                accF[m] = __builtin_amdgcn_mfma_f32_16x16x32_f16(al, fgb[kb+ks], accF[m], 0,0,0);
            }
        }
    };

    // ---- prologue ----
    loadst(0);
    scratch_write();      // waits load(0) via counted vmcnt
    loadst(1);            // in flight across barrier
    bar_lds();
    xpose(0);             // stage-0 tile -> buf0
    bar_lds();

    // ---- 32 stages ----
    #pragma unroll 1
    for (int s = 0; s < 32; s++) {
        if (s < 31) {
            scratch_write();            // stage s+1 data (waits its loads)
            if (s + 2 < 32) loadst(s + 2);
        }
        bar_lds();
        mfmast(s);
        if (s < 31) xpose((s + 1) & 1);
        if (s & 1) {                    // end of row: fold K-complete accs
            #pragma unroll
            for (int m = 0; m < 4; m++) {
                #pragma unroll
                for (int q = 0; q < 4; q++) {
                    vmaxF[m] = fmaxf(vmaxF[m], accF[m][q]);
                    vmaxH[m] = fmaxf(vmaxH[m], accH[m][q]);
                }
                accF[m] = (f32x4_t){0,0,0,0};
                accH[m] = (f32x4_t){0,0,0,0};
            }
        }
        bar_lds();
    }

    // ---- finalize: reduce pos-row groups, add bias, store ----
    #pragma unroll
    for (int m = 0; m < 4; m++) {
        float vF = vmaxF[m], vH = vmaxH[m];
        vF = fmaxf(vF, __shfl_xor(vF, 16, 64));
        vF = fmaxf(vF, __shfl_xor(vF, 32, 64));
        vH = fmaxf(vH, __shfl_xor(vH, 16, 64));
        vH = fmaxf(vH, __shfl_xor(vH, 32, 64));
        if (lane < 16) {
            const int win = wi*16 + wjg*4 + m;
            pooled_fg[((b*256 + wave*16 + lane) << 8) + win] = vF + biasF;
            pooledT_h[((b*256 + win) << 8) + wave*16 + lane] = vH + biasH;
        }
    }
}

// ---------------- kernel 3: dots + softmax + PV (all fp32) ----------------
__global__ __launch_bounds__(256) void k_attn(
    const float* __restrict__ pooled_fg, const float* __restrict__ pooledT_h,
    float* __restrict__ attnout)   // [B][256][256]
{
    __shared__ float red[4];
    __shared__ float p_lds[256];
    const int blk = blockIdx.x;
    const int b = blk >> 8;
    const int q = blk & 255;
    const int t = threadIdx.x;

    const float* fv = pooled_fg + ((b*256) << 8) + q;         // fv[c][q]
    const float* gv = pooled_fg + ((b*256 + 128) << 8) + t;   // gv[c][t]

    float s = 0.f;
    #pragma unroll 8
    for (int c = 0; c < 128; c++)
        s += fv[c << 8] * gv[c << 8];

    float m = s;
    #pragma unroll
    for (int o = 1; o < 64; o <<= 1) m = fmaxf(m, __shfl_xor(m, o, 64));
    if ((t & 63) == 0) red[t >> 6] = m;
    __syncthreads();
    m = fmaxf(fmaxf(red[0], red[1]), fmaxf(red[2], red[3]));
    __syncthreads();

    float p = expf(s - m);
    float sum = p;
    #pragma unroll
    for (int o = 1; o < 64; o <<= 1) sum += __shfl_xor(sum, o, 64);
    if ((t & 63) == 0) red[t >> 6] = sum;
    __syncthreads();
    sum = red[0] + red[1] + red[2] + red[3];
    p /= sum;
    p_lds[t] = p;
    __syncthreads();

    const float* hv = pooledT_h + (b << 16) + t;
    float acc = 0.f;
    #pragma unroll 8
    for (int k = 0; k < 256; k++)
        acc += p_lds[k] * hv[k << 8];
    attnout[((b*256 + t) << 8) + q] = acc;
}

// ---------------- kernel 4: bilinear 16x upsample (half-pixel, edge-clamped) + x ----
__global__ __launch_bounds__(256) void k_upsample_add(
    const float* __restrict__ x, const float* __restrict__ attnout,
    float* __restrict__ out)
{
    __shared__ float L[256];
    const int blk = blockIdx.x;            // b*256 + c
    const int t = threadIdx.x;
    L[t] = attnout[(blk << 8) + t];
    __syncthreads();
    const float* xp = x   + (size_t)blk * 65536;
    float*       op = out + (size_t)blk * 65536;

    const int x4 = (t & 63) << 2;
    const int yo = t >> 6;
    float fxv[4]; int x0v[4], x1v[4];
    #pragma unroll
    for (int e = 0; e < 4; e++) {
        float sx  = (x4 + e + 0.5f) * 0.0625f - 0.5f;
        float x0f = floorf(sx);
        fxv[e] = sx - x0f;
        int ix0 = (int)x0f;
        x0v[e] = min(15, max(0, ix0));
        x1v[e] = min(15, max(0, ix0 + 1));
    }
    for (int it = 0; it < 64; it++) {
        int y = it*4 + yo;
        float sy  = (y + 0.5f) * 0.0625f - 0.5f;
        float y0f = floorf(sy);
        float fy  = sy - y0f;
        int iy0 = (int)y0f;
        int y0 = min(15, max(0, iy0));
        int y1 = min(15, max(0, iy0 + 1));
        const float* Ly0 = L + y0*16;
        const float* Ly1 = L + y1*16;
        float4 xin = *(const float4*)(xp + y*256 + x4);
        float o[4]; const float* xe = (const float*)&xin;
        #pragma unroll
        for (int e = 0; e < 4; e++) {
            float top = Ly0[x0v[e]] + fxv[e] * (Ly0[x1v[e]] - Ly0[x0v[e]]);
            float bot = Ly1[x0v[e]] + fxv[e] * (Ly1[x1v[e]] - Ly1[x0v[e]]);
            o[e] = top + fy * (bot - top) + xe[e];
        }
        float4 ov = make_float4(o[0], o[1], o[2], o[3]);
        *(float4*)(op + y*256 + x4) = ov;
    }
}

extern "C" void kernel_launch(void* const* d_in, const int* in_sizes, int n_in,
                              void* d_out, int out_size, void* d_ws, size_t ws_size,
                              hipStream_t stream)
{
    const float* x   = (const float*)d_in[0];
    const float* f_w = (const float*)d_in[1];
    const float* f_b = (const float*)d_in[2];
    const float* g_w = (const float*)d_in[3];
    const float* g_b = (const float*)d_in[4];
    const float* h_w = (const float*)d_in[5];
    const float* h_b = (const float*)d_in[6];
    float* out = (float*)d_out;

    char* ws = (char*)d_ws;
    f16*   wf        = (f16*)ws;                              // 256 KB
    float* pooled_fg = (float*)(ws + (256<<10));              // 1 MB  [B][256][256]
    float* pooledT_h = (float*)(ws + (256<<10) + (1<<20));    // 1 MB  [B][256][256]
    float* attnout   = (float*)(ws + (256<<10) + (2<<20));    // 1 MB  [B][256][256]

    k_convert_w   <<<512, 256, 0, stream>>>(f_w, g_w, h_w, wf);
    k_pooled_conv <<<256, 1024, 0, stream>>>(x, wf, f_b, g_b, h_b, pooled_fg, pooledT_h);
    k_attn        <<<1024, 256, 0, stream>>>(pooled_fg, pooledT_h, attnout);
    k_upsample_add<<<1024, 256, 0, stream>>>(x, attnout, out);
}